// Round 5
// baseline (338.490 us; speedup 1.0000x reference)
//
#include <hip/hip_runtime.h>

typedef __bf16 bf16x8 __attribute__((ext_vector_type(8)));
typedef __bf16 bf16x4 __attribute__((ext_vector_type(4)));
typedef float  f32x4  __attribute__((ext_vector_type(4)));
typedef float  f32x4u __attribute__((ext_vector_type(4), aligned(4)));  // 4B-aligned vec

// Shapes: B=64, C=256, T=128, V=25, K=3, G=4, Cg=64, dk=16
// ws: xm f32 @0 (1,638,400 B) | afull bf16 @1,638,400 (393,216 B) | wcb bf16 @2,031,616 (98,304 B)

// ---- Kernel 1: temporal mean (pure stream, deterministic tree-sum) ----
// block=(b, c-pair). Thread r reads quads r+125*i of its channel: contiguous
// 1KB per wave-instr, and 4*quad mod 25 is constant per thread -> f32x4 acc
// has a fixed v-phase. 4KB LDS partials, 50-thread ordered reduction.
__global__ __launch_bounds__(256)
void k_tmean4(const float* __restrict__ x, float* __restrict__ xm)
{
    const int bid = blockIdx.x;            // b*128 + c2
    const int b = bid >> 7, c2 = bid & 127;
    const int tid = threadIdx.x;
    const int c_loc = tid >> 7, r = tid & 127;

    __shared__ float xpart[2][25][5][4];   // 4 KB

    if (r < 125) {
        const float* base = x + (size_t)(b * 256 + c2 * 2 + c_loc) * 3200;
        f32x4 acc = {0.f, 0.f, 0.f, 0.f};
#pragma unroll
        for (int i = 0; i < 7; ++i) {
            const int q = r + 125 * i;
            if (q < 800) {
                f32x4 v4 = *(const f32x4*)(base + q * 4);   // 16B-aligned
                acc += v4;
            }
        }
        const int vq = r % 25, jg = r / 25;
        *(f32x4*)(&xpart[c_loc][vq][jg][0]) = acc;
    }
    __syncthreads();
    if (tid < 50) {
        const int cl = tid / 25, v = tid - cl * 25;
        float s = 0.f;
#pragma unroll
        for (int e = 0; e < 4; ++e) {
            const int vq = (((v - e + 25) % 25) * 19) % 25;  // 4*vq == v-e (mod 25)
#pragma unroll
            for (int j = 0; j < 5; ++j) s += xpart[cl][vq][j][e];
        }
        xm[((size_t)(b * 256) + c2 * 2 + cl) * 25 + v] = s * (1.0f / 128.0f);
    }
}

// ---- Kernel 2: A_dyn + Afull tables + Wconv->bf16 (one block per b) ----
__global__ __launch_bounds__(256)
void k_adyn(const float* __restrict__ xm, const float* __restrict__ A,
            const float* __restrict__ Wq, const float* __restrict__ Wk,
            const float* __restrict__ alpha, __bf16* __restrict__ afull,
            const float* __restrict__ Wconv, __bf16* __restrict__ wcb)
{
    const int b = blockIdx.x, tid = threadIdx.x;
    __shared__ float xm_s[256 * 25];
    __shared__ float q_s[64 * 25];
    __shared__ float k_s[64 * 25];
    __shared__ float sm_s[4][25][25];
    __shared__ float ad_s[25][25];
    __shared__ float rs_s[3][25];

    for (int i = tid; i < 768; i += 256)
        wcb[b * 768 + i] = (__bf16)Wconv[b * 768 + i];

    for (int i = tid; i < 256 * 25; i += 256) xm_s[i] = xm[(size_t)b * 6400 + i];
    for (int i = tid; i < 75; i += 256) {
        int k3 = i / 25, v = i - (i / 25) * 25;
        float s = 0.f;
        for (int w = 0; w < 25; ++w) s += A[(k3 * 25 + v) * 25 + w];
        rs_s[k3][v] = fmaxf(s, 1e-6f);
    }
    __syncthreads();

    for (int i = tid; i < 1600; i += 256) {
        int o = i / 25, v = i - o * 25;
        const float* wq = Wq + o * 256;
        const float* wk = Wk + o * 256;
        float aq = 0.f, ak = 0.f;
        for (int c4 = 0; c4 < 256; c4 += 4) {
            f32x4 q4 = *(const f32x4*)(wq + c4);
            f32x4 k4 = *(const f32x4*)(wk + c4);
#pragma unroll
            for (int e = 0; e < 4; ++e) {
                const float xv = xm_s[(c4 + e) * 25 + v];
                aq += q4[e] * xv;
                ak += k4[e] * xv;
            }
        }
        q_s[i] = aq; k_s[i] = ak;
    }
    __syncthreads();

    if (tid < 100) {
        int g = tid / 25, v = tid - (tid / 25) * 25;
        float l[25];
#pragma unroll
        for (int w = 0; w < 25; ++w) {
            float s = 0.f;
#pragma unroll
            for (int d = 0; d < 16; ++d)
                s += q_s[(g * 16 + d) * 25 + v] * k_s[(g * 16 + d) * 25 + w];
            l[w] = s * 0.25f;
        }
        float mx = l[0];
#pragma unroll
        for (int w = 1; w < 25; ++w) mx = fmaxf(mx, l[w]);
        float den = 0.f;
#pragma unroll
        for (int w = 0; w < 25; ++w) { l[w] = expf(l[w] - mx); den += l[w]; }
        float rden = 1.f / den;
#pragma unroll
        for (int w = 0; w < 25; ++w) sm_s[g][v][w] = l[w] * rden;
    }
    __syncthreads();
    for (int i = tid; i < 625; i += 256) {
        int v = i / 25, w = i - (i / 25) * 25;
        ad_s[v][w] = 0.25f * (sm_s[0][v][w] + sm_s[1][v][w] + sm_s[2][v][w] + sm_s[3][v][w]);
    }
    __syncthreads();

    const float al = tanhf(alpha[0]);
    for (int i = tid; i < 3 * 32 * 32; i += 256) {
        int k3 = i >> 10, rem = i & 1023, v = rem >> 5, w = rem & 31;
        float val = 0.f;
        if (v < 25 && w < 25)
            val = A[(k3 * 25 + v) * 25 + w] / rs_s[k3][v] + al * ad_s[v][w];
        afull[(size_t)b * 3072 + i] = (__bf16)val;
    }
}

// ---- Kernel 3: BARRIER-FREE fused agg+conv+BN+residual ----
// block=(b,g,tt of 4 t); wave w owns t = tt*4+w entirely. Agg writes the
// wave's own 25x64 LDS region; conv reads only those rows (per-wave DS
// in-order => no __syncthreads anywhere). x read directly as f32 (4B-aligned
// vec loads); v>=25 garbage in A-frags is nulled by Afull's zero pad rows.
__global__ __launch_bounds__(256, 4)
void k_main4(const float* __restrict__ x, const __bf16* __restrict__ wcb,
             const __bf16* __restrict__ afull,
             const float* __restrict__ gamma, const float* __restrict__ beta,
             const float* __restrict__ rmean, const float* __restrict__ rvar,
             float* __restrict__ out)
{
    const int bid = blockIdx.x;
    const int tt = bid & 31;
    const int g  = (bid >> 5) & 3;
    const int b  = bid >> 7;
    const int tid = threadIdx.x;
    const int wave = tid >> 6, lane = tid & 63, l15 = lane & 15, lg = lane >> 4;
    const int t = tt * 4 + wave;

    __shared__ __bf16 xagg[4][32][64];   // 16 KB; rows 25..31 zeroed per wave
    __bf16* myagg = &xagg[wave][0][0];

    // zero own pad rows 25..31 (one masked b128 store)
    if (lane < 56) {
        const int rr = 25 + (lane >> 3), cw = (lane & 7) * 8;
        bf16x8 z;
#pragma unroll
        for (int e = 0; e < 8; ++e) z[e] = (__bf16)0.f;
        *(bf16x8*)(&myagg[rr * 64 + cw]) = z;
    }

    // x A-frags: A[row=c][k=v]; lane(l15,lg) = x[c=m*16+l15][t][v=lg*8..+7]
    const float* xbase = x + (size_t)(b * 256 + g * 64) * 3200 + t * 25;
    bf16x8 xfrag[4];
#pragma unroll
    for (int m = 0; m < 4; ++m) {
        const float* p = xbase + (size_t)(m * 16 + l15) * 3200 + lg * 8;
        bf16x8 f;
        if (lg < 3) {
            f32x4u a0 = *(const f32x4u*)(p);
            f32x4u a1 = *(const f32x4u*)(p + 4);
#pragma unroll
            for (int e = 0; e < 4; ++e) { f[e] = (__bf16)a0[e]; f[e + 4] = (__bf16)a1[e]; }
        } else {                          // v=24 only; 25..31 would be OOB/garbage
            f[0] = (__bf16)p[0];
#pragma unroll
            for (int e = 1; e < 8; ++e) f[e] = (__bf16)0.f;
        }
        xfrag[m] = f;
    }

    // BN constants (per conv N-tile nt: o = nt*16+l15)
    float inv_[4], bias_[4];
#pragma unroll
    for (int nt = 0; nt < 4; ++nt) {
        const int chn = g * 64 + nt * 16 + l15;
        const float iv = gamma[chn] / sqrtf(rvar[chn] + 1e-5f);
        inv_[nt] = iv;
        bias_[nt] = beta[chn] - rmean[chn] * iv;
    }

    // Afull B-frags, all 3 k (L2/L3-hot)
    const __bf16* ab = afull + ((size_t)(b * 3) << 10) + l15 * 32 + lg * 8;
    bf16x8 bA[3][2];
#pragma unroll
    for (int k3 = 0; k3 < 3; ++k3) {
        bA[k3][0] = *(const bf16x8*)(ab + k3 * 1024);
        bA[k3][1] = *(const bf16x8*)(ab + k3 * 1024 + 512);
    }

    f32x4 acc[2][4];
#pragma unroll
    for (int mt = 0; mt < 2; ++mt)
#pragma unroll
        for (int nt = 0; nt < 4; ++nt) acc[mt][nt] = (f32x4){0.f, 0.f, 0.f, 0.f};
    const f32x4 zero4 = {0.f, 0.f, 0.f, 0.f};
    const int swz = (l15 & 7) << 3;

#pragma unroll
    for (int k3 = 0; k3 < 3; ++k3) {
        // aggregation: D[c-row, v-col] -> own LDS rows [v][c] (swizzled)
#pragma unroll
        for (int m = 0; m < 4; ++m) {
#pragma unroll
            for (int n = 0; n < 2; ++n) {
                f32x4 d = __builtin_amdgcn_mfma_f32_16x16x32_bf16(xfrag[m], bA[k3][n],
                                                                  zero4, 0, 0, 0);
                const int v = n * 16 + l15;
                if (v < 25) {
                    const int col = (m * 16 + lg * 4) ^ ((v & 7) << 3);
                    bf16x4 h;
                    h[0] = (__bf16)d[0]; h[1] = (__bf16)d[1];
                    h[2] = (__bf16)d[2]; h[3] = (__bf16)d[3];
                    *(bf16x4*)(&myagg[v * 64 + col]) = h;
                }
            }
        }
        // conv: acc[v-rows, o] += xagg[v, c] * W[o, c]  (own rows only)
#pragma unroll
        for (int kk = 0; kk < 2; ++kk) {
            const int cbase = kk * 32 + lg * 8;
            bf16x8 aF0 = *(const bf16x8*)(&myagg[l15 * 64 + (cbase ^ swz)]);
            bf16x8 aF1 = *(const bf16x8*)(&myagg[(16 + l15) * 64 + (cbase ^ swz)]);
#pragma unroll
            for (int nt = 0; nt < 4; ++nt) {
                bf16x8 wf = *(const bf16x8*)(wcb +
                    (size_t)((k3 * 4 + g) * 64 + nt * 16 + l15) * 64 + cbase);
                acc[0][nt] = __builtin_amdgcn_mfma_f32_16x16x32_bf16(aF0, wf, acc[0][nt], 0, 0, 0);
                acc[1][nt] = __builtin_amdgcn_mfma_f32_16x16x32_bf16(aF1, wf, acc[1][nt], 0, 0, 0);
            }
        }
    }

    // epilogue: out = x + acc*inv + bias (residual f32, L1-hot lines)
#pragma unroll
    for (int nt = 0; nt < 4; ++nt) {
        const int chn = g * 64 + nt * 16 + l15;
        const float* rp = x + (size_t)(b * 256 + chn) * 3200 + t * 25;
        float* op = out + (size_t)(b * 256 + chn) * 3200 + t * 25;
#pragma unroll
        for (int mt = 0; mt < 2; ++mt) {
            const int cc0 = mt * 16 + lg * 4;
            if (cc0 + 3 < 25) {
                f32x4u r4 = *(const f32x4u*)(rp + cc0);
                f32x4u o4;
#pragma unroll
                for (int e = 0; e < 4; ++e)
                    o4[e] = r4[e] + acc[mt][nt][e] * inv_[nt] + bias_[nt];
                *(f32x4u*)(op + cc0) = o4;
            } else if (cc0 < 25) {
#pragma unroll
                for (int e = 0; e < 4; ++e) {
                    const int cc = cc0 + e;
                    if (cc < 25)
                        op[cc] = rp[cc] + acc[mt][nt][e] * inv_[nt] + bias_[nt];
                }
            }
        }
    }
}

extern "C" void kernel_launch(void* const* d_in, const int* in_sizes, int n_in,
                              void* d_out, int out_size, void* d_ws, size_t ws_size,
                              hipStream_t stream) {
    const float* x     = (const float*)d_in[0];
    const float* A     = (const float*)d_in[1];
    const float* Wq    = (const float*)d_in[2];
    const float* Wk    = (const float*)d_in[3];
    const float* Wconv = (const float*)d_in[4];
    const float* alpha = (const float*)d_in[5];
    const float* gamma = (const float*)d_in[6];
    const float* beta  = (const float*)d_in[7];
    const float* rmean = (const float*)d_in[8];
    const float* rvar  = (const float*)d_in[9];
    float* out = (float*)d_out;

    float*  xm    = (float*)d_ws;
    __bf16* afull = (__bf16*)((char*)d_ws + 1638400);
    __bf16* wcb   = (__bf16*)((char*)d_ws + 2031616);

    k_tmean4<<<64 * 128, 256, 0, stream>>>(x, xm);
    k_adyn<<<64, 256, 0, stream>>>(xm, A, Wq, Wk, alpha, afull, Wconv, wcb);
    k_main4<<<64 * 4 * 32, 256, 0, stream>>>(x, wcb, afull, gamma, beta,
                                             rmean, rvar, out);
}

// Round 7
// 216.004 us; speedup vs baseline: 1.5670x; 1.5670x over previous
//
#include <hip/hip_runtime.h>

typedef __bf16 bf16x8 __attribute__((ext_vector_type(8)));
typedef __bf16 bf16x4 __attribute__((ext_vector_type(4)));
typedef float  f32x4  __attribute__((ext_vector_type(4)));

// Shapes: B=64, C=256, T=128, V=25, K=3, G=4, Cg=64, dk=16
// ws: xm f32 @0 | afull bf16 @1,638,400 | wcb bf16 @2,031,616

// ---- Kernel 1: temporal mean (pure stream, deterministic tree-sum) [R5-verified] ----
__global__ __launch_bounds__(256)
void k_tmean4(const float* __restrict__ x, float* __restrict__ xm)
{
    const int bid = blockIdx.x;            // b*128 + c2
    const int b = bid >> 7, c2 = bid & 127;
    const int tid = threadIdx.x;
    const int c_loc = tid >> 7, r = tid & 127;

    __shared__ float xpart[2][25][5][4];   // 4 KB

    if (r < 125) {
        const float* base = x + (size_t)(b * 256 + c2 * 2 + c_loc) * 3200;
        f32x4 acc = {0.f, 0.f, 0.f, 0.f};
#pragma unroll
        for (int i = 0; i < 7; ++i) {
            const int q = r + 125 * i;
            if (q < 800) {
                f32x4 v4 = *(const f32x4*)(base + q * 4);   // 16B-aligned
                acc += v4;
            }
        }
        const int vq = r % 25, jg = r / 25;
        *(f32x4*)(&xpart[c_loc][vq][jg][0]) = acc;
    }
    __syncthreads();
    if (tid < 50) {
        const int cl = tid / 25, v = tid - cl * 25;
        float s = 0.f;
#pragma unroll
        for (int e = 0; e < 4; ++e) {
            const int vq = (((v - e + 25) % 25) * 19) % 25;  // 4*vq == v-e (mod 25)
#pragma unroll
            for (int j = 0; j < 5; ++j) s += xpart[cl][vq][j][e];
        }
        xm[((size_t)(b * 256) + c2 * 2 + cl) * 25 + v] = s * (1.0f / 128.0f);
    }
}

// ---- Kernel 2: A_dyn + Afull tables + Wconv->bf16 (one block per b) [R4-verified] ----
__global__ __launch_bounds__(256)
void k_adyn(const float* __restrict__ xm, const float* __restrict__ A,
            const float* __restrict__ Wq, const float* __restrict__ Wk,
            const float* __restrict__ alpha, __bf16* __restrict__ afull,
            const float* __restrict__ Wconv, __bf16* __restrict__ wcb)
{
    const int b = blockIdx.x, tid = threadIdx.x;
    __shared__ float xm_s[256 * 25];
    __shared__ float q_s[64 * 25];
    __shared__ float k_s[64 * 25];
    __shared__ float sm_s[4][25][25];
    __shared__ float ad_s[25][25];
    __shared__ float rs_s[3][25];

    for (int i = tid; i < 768; i += 256)
        wcb[b * 768 + i] = (__bf16)Wconv[b * 768 + i];

    for (int i = tid; i < 256 * 25; i += 256) xm_s[i] = xm[(size_t)b * 6400 + i];
    for (int i = tid; i < 75; i += 256) {
        int k3 = i / 25, v = i - (i / 25) * 25;
        float s = 0.f;
        for (int w = 0; w < 25; ++w) s += A[(k3 * 25 + v) * 25 + w];
        rs_s[k3][v] = fmaxf(s, 1e-6f);
    }
    __syncthreads();

    for (int i = tid; i < 1600; i += 256) {
        int o = i / 25, v = i - o * 25;
        const float* wq = Wq + o * 256;
        const float* wk = Wk + o * 256;
        float aq = 0.f, ak = 0.f;
        for (int c4 = 0; c4 < 256; c4 += 4) {
            f32x4 q4 = *(const f32x4*)(wq + c4);
            f32x4 k4 = *(const f32x4*)(wk + c4);
#pragma unroll
            for (int e = 0; e < 4; ++e) {
                const float xv = xm_s[(c4 + e) * 25 + v];
                aq += q4[e] * xv;
                ak += k4[e] * xv;
            }
        }
        q_s[i] = aq; k_s[i] = ak;
    }
    __syncthreads();

    if (tid < 100) {
        int g = tid / 25, v = tid - (tid / 25) * 25;
        float l[25];
#pragma unroll
        for (int w = 0; w < 25; ++w) {
            float s = 0.f;
#pragma unroll
            for (int d = 0; d < 16; ++d)
                s += q_s[(g * 16 + d) * 25 + v] * k_s[(g * 16 + d) * 25 + w];
            l[w] = s * 0.25f;
        }
        float mx = l[0];
#pragma unroll
        for (int w = 1; w < 25; ++w) mx = fmaxf(mx, l[w]);
        float den = 0.f;
#pragma unroll
        for (int w = 0; w < 25; ++w) { l[w] = expf(l[w] - mx); den += l[w]; }
        float rden = 1.f / den;
#pragma unroll
        for (int w = 0; w < 25; ++w) sm_s[g][v][w] = l[w] * rden;
    }
    __syncthreads();
    for (int i = tid; i < 625; i += 256) {
        int v = i / 25, w = i - (i / 25) * 25;
        ad_s[v][w] = 0.25f * (sm_s[0][v][w] + sm_s[1][v][w] + sm_s[2][v][w] + sm_s[3][v][w]);
    }
    __syncthreads();

    const float al = tanhf(alpha[0]);
    for (int i = tid; i < 3 * 32 * 32; i += 256) {
        int k3 = i >> 10, rem = i & 1023, v = rem >> 5, w = rem & 31;
        float val = 0.f;
        if (v < 25 && w < 25)
            val = A[(k3 * 25 + v) * 25 + w] / rs_s[k3][v] + al * ad_s[v][w];
        afull[(size_t)b * 3072 + i] = (__bf16)val;
    }
}

// ---- Kernel 3: fused agg (MFMA) + grouped conv (MFMA) + BN + residual [R2-verified] ----
// block = (b, g, tt of 4 t). LDS: xs bf16 swizzled [c][t][32] (16 KB) + xagg [112][64] (14.3 KB).
__global__ __launch_bounds__(256, 4)
void k_main(const float* __restrict__ x, const float* __restrict__ Wconv,
            const __bf16* __restrict__ afull,
            const float* __restrict__ gamma, const float* __restrict__ beta,
            const float* __restrict__ rmean, const float* __restrict__ rvar,
            float* __restrict__ out)
{
    const int bid = blockIdx.x;
    const int tt = bid & 31;
    const int g  = (bid >> 5) & 3;
    const int b  = bid >> 7;
    const int tid = threadIdx.x;
    const int wave = tid >> 6;
    const int lane = tid & 63;
    const int l15 = lane & 15;
    const int lg  = lane >> 4;

    __shared__ __bf16 xs[64 * 4 * 32];     // 16 KB
    __shared__ __bf16 xagg[112 * 64];      // 14.3 KB

    // ---- stage x slice -> xs (bf16, swizzled); thread = (c, t) row ----
    {
        const int c = tid >> 2, t = tid & 3;
        const float* p = x + ((size_t)(b * 256 + g * 64 + c) * 128 + tt * 4 + t) * 25;
        float r[25];
#pragma unroll
        for (int j = 0; j < 25; ++j) r[j] = p[j];
        const int rowg = (c * 4 + t) << 2;
        const int sw = c & 7;
#pragma unroll
        for (int ch = 0; ch < 4; ++ch) {
            bf16x8 h;
#pragma unroll
            for (int e = 0; e < 8; ++e) {
                const int v = ch * 8 + e;
                h[e] = (v < 25) ? (__bf16)r[v] : (__bf16)0.f;
            }
            *(bf16x8*)((char*)xs + (((rowg | ch) ^ sw) << 4)) = h;
        }
    }

    // ---- prefetch A-tables (all 3 k), issue Wconv k=0 loads ----
    bf16x8 bAf[3][2];
#pragma unroll
    for (int k3 = 0; k3 < 3; ++k3)
#pragma unroll
        for (int n = 0; n < 2; ++n)
            bAf[k3][n] = *(const bf16x8*)(afull + ((size_t)(b * 3 + k3) << 10) +
                                          (n * 16 + l15) * 32 + lg * 8);

    const int o_lane = (wave << 4) + l15;
    f32x4 wff[4];                          // in-flight f32 Wconv
    {
        const float* wp = Wconv + (size_t)((0 * 4 + g) * 64 + o_lane) * 64 + lg * 8;
        wff[0] = *(const f32x4*)wp;        wff[1] = *(const f32x4*)(wp + 4);
        wff[2] = *(const f32x4*)(wp + 32); wff[3] = *(const f32x4*)(wp + 36);
    }

    const int ch = g * 64 + o_lane;
    const float inv  = gamma[ch] / sqrtf(rvar[ch] + 1e-5f);
    const float bias = beta[ch] - rmean[ch] * inv;

    __syncthreads();

    // ---- fragments: lane (l15, lg) reads xs[c = m*16+l15][t=wave][chunk=lg] ----
    bf16x8 xfrag[4];
#pragma unroll
    for (int m = 0; m < 4; ++m) {
        const int c = m * 16 + l15;
        xfrag[m] = *(const bf16x8*)((char*)xs +
                      (((((c * 4 + wave) << 2) | lg) ^ (c & 7)) << 4));
    }

    f32x4 acc[7];
#pragma unroll
    for (int i = 0; i < 7; ++i) acc[i] = (f32x4){0.f, 0.f, 0.f, 0.f};
    const f32x4 zero4 = {0.f, 0.f, 0.f, 0.f};
    bf16x8 wfc[2];

#pragma unroll
    for (int k3 = 0; k3 < 3; ++k3) {
        // convert the in-flight Wconv f32 -> bf16 fragments
#pragma unroll
        for (int ks = 0; ks < 2; ++ks) {
            bf16x8 h;
#pragma unroll
            for (int e = 0; e < 4; ++e) {
                h[e]     = (__bf16)wff[ks * 2][e];
                h[e + 4] = (__bf16)wff[ks * 2 + 1][e];
            }
            wfc[ks] = h;
        }
        if (k3 < 2) {   // issue next k's Wconv loads (land during conv phase)
            const float* wp = Wconv + (size_t)(((k3 + 1) * 4 + g) * 64 + o_lane) * 64 + lg * 8;
            wff[0] = *(const f32x4*)wp;        wff[1] = *(const f32x4*)(wp + 4);
            wff[2] = *(const f32x4*)(wp + 32); wff[3] = *(const f32x4*)(wp + 36);
        }

        if (k3 > 0) __syncthreads();   // previous conv reads done before overwrite

        // aggregation: D[(t=wave, c-block m), v] -> xagg (swizzled bf16)
#pragma unroll
        for (int m = 0; m < 4; ++m) {
#pragma unroll
            for (int n = 0; n < 2; ++n) {
                f32x4 d = __builtin_amdgcn_mfma_f32_16x16x32_bf16(xfrag[m], bAf[k3][n],
                                                                  zero4, 0, 0, 0);
                const int v = n * 16 + l15;
                if (v < 25) {
                    const int cc  = wave * 25 + v;
                    const int col = (m * 16 + lg * 4) ^ ((cc & 7) << 3);
                    bf16x4 h;
                    h[0] = (__bf16)d[0]; h[1] = (__bf16)d[1];
                    h[2] = (__bf16)d[2]; h[3] = (__bf16)d[3];
                    *(bf16x4*)((char*)xagg + cc * 128 + col * 2) = h;
                }
            }
        }
        __syncthreads();

        // conv: acc[cc-tile, o] += xagg[cc, c] * W[o, c]
#pragma unroll
        for (int mcc = 0; mcc < 7; ++mcc) {
            const int cc = mcc * 16 + l15;
            const int sw2 = (cc & 7) << 3;
#pragma unroll
            for (int ks = 0; ks < 2; ++ks) {
                const int col = (ks * 32 + lg * 8) ^ sw2;
                bf16x8 aF = *(const bf16x8*)((char*)xagg + cc * 128 + col * 2);
                acc[mcc] = __builtin_amdgcn_mfma_f32_16x16x32_bf16(aF, wfc[ks],
                                                                   acc[mcc], 0, 0, 0);
            }
        }
        if (k3 < 2) __syncthreads();
    }

    // ---- epilogue: out = x + acc*inv + bias (residual from staged bf16 xs) ----
    const size_t obase = (size_t)(b * 256 + ch) * 3200 + tt * 100;
#pragma unroll
    for (int mcc = 0; mcc < 7; ++mcc) {
        const int cc0 = mcc * 16 + lg * 4;
        if (cc0 < 100) {
            f32x4 o4;
#pragma unroll
            for (int j = 0; j < 4; ++j) {
                const int cc = cc0 + j;
                const int t = cc / 25, v = cc - t * 25;
                const int gr = (((o_lane * 4 + t) << 2) | (v >> 3)) ^ (o_lane & 7);
                const float xr = (float)*(const __bf16*)((char*)xs + (gr << 4) + ((v & 7) << 1));
                o4[j] = xr + acc[mcc][j] * inv + bias;
            }
            *(f32x4*)(out + obase + cc0) = o4;
        }
    }
}

extern "C" void kernel_launch(void* const* d_in, const int* in_sizes, int n_in,
                              void* d_out, int out_size, void* d_ws, size_t ws_size,
                              hipStream_t stream) {
    const float* x     = (const float*)d_in[0];
    const float* A     = (const float*)d_in[1];
    const float* Wq    = (const float*)d_in[2];
    const float* Wk    = (const float*)d_in[3];
    const float* Wconv = (const float*)d_in[4];
    const float* alpha = (const float*)d_in[5];
    const float* gamma = (const float*)d_in[6];
    const float* beta  = (const float*)d_in[7];
    const float* rmean = (const float*)d_in[8];
    const float* rvar  = (const float*)d_in[9];
    float* out = (float*)d_out;

    float*  xm    = (float*)d_ws;
    __bf16* afull = (__bf16*)((char*)d_ws + 1638400);
    __bf16* wcb   = (__bf16*)((char*)d_ws + 2031616);

    k_tmean4<<<64 * 128, 256, 0, stream>>>(x, xm);
    k_adyn<<<64, 256, 0, stream>>>(xm, A, Wq, Wk, alpha, afull, Wconv, wcb);
    k_main<<<64 * 4 * 32, 256, 0, stream>>>(x, Wconv, afull, gamma, beta,
                                            rmean, rvar, out);
}

// Round 9
// 192.977 us; speedup vs baseline: 1.7540x; 1.1193x over previous
//
#include <hip/hip_runtime.h>

typedef __bf16 bf16x8 __attribute__((ext_vector_type(8)));
typedef __bf16 bf16x4 __attribute__((ext_vector_type(4)));
typedef float  f32x4  __attribute__((ext_vector_type(4)));

// Shapes: B=64, C=256, T=128, V=25, K=3, G=4, Cg=64, dk=16
// ws: xm f32 @0 | afull bf16 @1,638,400 | wcb bf16 @2,031,616

// ---- Kernel 1: temporal mean (pure stream, deterministic tree-sum) [R5/R7-verified] ----
__global__ __launch_bounds__(256)
void k_tmean4(const float* __restrict__ x, float* __restrict__ xm)
{
    const int bid = blockIdx.x;            // b*128 + c2
    const int b = bid >> 7, c2 = bid & 127;
    const int tid = threadIdx.x;
    const int c_loc = tid >> 7, r = tid & 127;

    __shared__ float xpart[2][25][5][4];   // 4 KB

    if (r < 125) {
        const float* base = x + (size_t)(b * 256 + c2 * 2 + c_loc) * 3200;
        f32x4 acc = {0.f, 0.f, 0.f, 0.f};
#pragma unroll
        for (int i = 0; i < 7; ++i) {
            const int q = r + 125 * i;
            if (q < 800) {
                f32x4 v4 = *(const f32x4*)(base + q * 4);   // 16B-aligned
                acc += v4;
            }
        }
        const int vq = r % 25, jg = r / 25;
        *(f32x4*)(&xpart[c_loc][vq][jg][0]) = acc;
    }
    __syncthreads();
    if (tid < 50) {
        const int cl = tid / 25, v = tid - cl * 25;
        float s = 0.f;
#pragma unroll
        for (int e = 0; e < 4; ++e) {
            const int vq = (((v - e + 25) % 25) * 19) % 25;  // 4*vq == v-e (mod 25)
#pragma unroll
            for (int j = 0; j < 5; ++j) s += xpart[cl][vq][j][e];
        }
        xm[((size_t)(b * 256) + c2 * 2 + cl) * 25 + v] = s * (1.0f / 128.0f);
    }
}

// ---- Kernel 2: A_dyn + Afull tables + Wconv->bf16 (one block per b) [R4/R7-verified] ----
__global__ __launch_bounds__(256)
void k_adyn(const float* __restrict__ xm, const float* __restrict__ A,
            const float* __restrict__ Wq, const float* __restrict__ Wk,
            const float* __restrict__ alpha, __bf16* __restrict__ afull,
            const float* __restrict__ Wconv, __bf16* __restrict__ wcb)
{
    const int b = blockIdx.x, tid = threadIdx.x;
    __shared__ float xm_s[256 * 25];
    __shared__ float q_s[64 * 25];
    __shared__ float k_s[64 * 25];
    __shared__ float sm_s[4][25][25];
    __shared__ float ad_s[25][25];
    __shared__ float rs_s[3][25];

    for (int i = tid; i < 768; i += 256)
        wcb[b * 768 + i] = (__bf16)Wconv[b * 768 + i];

    for (int i = tid; i < 256 * 25; i += 256) xm_s[i] = xm[(size_t)b * 6400 + i];
    for (int i = tid; i < 75; i += 256) {
        int k3 = i / 25, v = i - (i / 25) * 25;
        float s = 0.f;
        for (int w = 0; w < 25; ++w) s += A[(k3 * 25 + v) * 25 + w];
        rs_s[k3][v] = fmaxf(s, 1e-6f);
    }
    __syncthreads();

    for (int i = tid; i < 1600; i += 256) {
        int o = i / 25, v = i - o * 25;
        const float* wq = Wq + o * 256;
        const float* wk = Wk + o * 256;
        float aq = 0.f, ak = 0.f;
        for (int c4 = 0; c4 < 256; c4 += 4) {
            f32x4 q4 = *(const f32x4*)(wq + c4);
            f32x4 k4 = *(const f32x4*)(wk + c4);
#pragma unroll
            for (int e = 0; e < 4; ++e) {
                const float xv = xm_s[(c4 + e) * 25 + v];
                aq += q4[e] * xv;
                ak += k4[e] * xv;
            }
        }
        q_s[i] = aq; k_s[i] = ak;
    }
    __syncthreads();

    if (tid < 100) {
        int g = tid / 25, v = tid - (tid / 25) * 25;
        float l[25];
#pragma unroll
        for (int w = 0; w < 25; ++w) {
            float s = 0.f;
#pragma unroll
            for (int d = 0; d < 16; ++d)
                s += q_s[(g * 16 + d) * 25 + v] * k_s[(g * 16 + d) * 25 + w];
            l[w] = s * 0.25f;
        }
        float mx = l[0];
#pragma unroll
        for (int w = 1; w < 25; ++w) mx = fmaxf(mx, l[w]);
        float den = 0.f;
#pragma unroll
        for (int w = 0; w < 25; ++w) { l[w] = expf(l[w] - mx); den += l[w]; }
        float rden = 1.f / den;
#pragma unroll
        for (int w = 0; w < 25; ++w) sm_s[g][v][w] = l[w] * rden;
    }
    __syncthreads();
    for (int i = tid; i < 625; i += 256) {
        int v = i / 25, w = i - (i / 25) * 25;
        ad_s[v][w] = 0.25f * (sm_s[0][v][w] + sm_s[1][v][w] + sm_s[2][v][w] + sm_s[3][v][w]);
    }
    __syncthreads();

    const float al = tanhf(alpha[0]);
    for (int i = tid; i < 3 * 32 * 32; i += 256) {
        int k3 = i >> 10, rem = i & 1023, v = rem >> 5, w = rem & 31;
        float val = 0.f;
        if (v < 25 && w < 25)
            val = A[(k3 * 25 + v) * 25 + w] / rs_s[k3][v] + al * ad_s[v][w];
        afull[(size_t)b * 3072 + i] = (__bf16)val;
    }
}

// ---- Kernel 3: R2 structure + XCD-contiguous swizzle (FIXED for 8192 blocks) ----
// block(orig) = (b, g, tt of 4 t). LDS: xs bf16 swizzled (16 KB) + xagg [112][64] (14.3 KB).
// Swizzle: XCD x owns orig range [x*1024,(x+1)*1024) -> same-(b,g) tt tiles are
// contiguous on one XCD's L2 -> dense 12.8KB/channel HBM streams (read & write).
__global__ __launch_bounds__(256, 4)
void k_main7(const float* __restrict__ x, const __bf16* __restrict__ wcb,
             const __bf16* __restrict__ afull,
             const float* __restrict__ gamma, const float* __restrict__ beta,
             const float* __restrict__ rmean, const float* __restrict__ rvar,
             float* __restrict__ out)
{
    const int orig = ((blockIdx.x & 7) << 10) | (blockIdx.x >> 3);  // bijective: 8192 blocks, 8192%8==0
    const int tt = orig & 31;
    const int g  = (orig >> 5) & 3;
    const int b  = orig >> 7;
    const int tid = threadIdx.x;
    const int wave = tid >> 6;
    const int lane = tid & 63;
    const int l15 = lane & 15;
    const int lg  = lane >> 4;

    __shared__ __bf16 xs[64 * 4 * 32];     // 16 KB
    __shared__ __bf16 xagg[112 * 64];      // 14.3 KB

    // ---- stage x slice -> xs (bf16, swizzled); thread = (c, t) row ----
    {
        const int c = tid >> 2, t = tid & 3;
        const float* p = x + ((size_t)(b * 256 + g * 64 + c) * 128 + tt * 4 + t) * 25;
        float r[25];
#pragma unroll
        for (int j = 0; j < 25; ++j) r[j] = p[j];
        const int rowg = (c * 4 + t) << 2;
        const int sw = c & 7;
#pragma unroll
        for (int ch = 0; ch < 4; ++ch) {
            bf16x8 h;
#pragma unroll
            for (int e = 0; e < 8; ++e) {
                const int v = ch * 8 + e;
                h[e] = (v < 25) ? (__bf16)r[v] : (__bf16)0.f;
            }
            *(bf16x8*)((char*)xs + (((rowg | ch) ^ sw) << 4)) = h;
        }
    }

    const int o_lane = (wave << 4) + l15;
    const int ch = g * 64 + o_lane;
    const float inv  = gamma[ch] / sqrtf(rvar[ch] + 1e-5f);
    const float bias = beta[ch] - rmean[ch] * inv;

    const __bf16* ab = afull + ((size_t)(b * 3) << 10) + l15 * 32 + lg * 8;
    const __bf16* wb = wcb + (size_t)(g * 64 + o_lane) * 64 + lg * 8;

    __syncthreads();

    // ---- fragments: lane (l15, lg) reads xs[c = m*16+l15][t=wave][chunk=lg] ----
    bf16x8 xfrag[4];
#pragma unroll
    for (int m = 0; m < 4; ++m) {
        const int c = m * 16 + l15;
        xfrag[m] = *(const bf16x8*)((char*)xs +
                      (((((c * 4 + wave) << 2) | lg) ^ (c & 7)) << 4));
    }

    f32x4 acc[7];
#pragma unroll
    for (int i = 0; i < 7; ++i) acc[i] = (f32x4){0.f, 0.f, 0.f, 0.f};
    const f32x4 zero4 = {0.f, 0.f, 0.f, 0.f};

#pragma unroll
    for (int k3 = 0; k3 < 3; ++k3) {
        // per-k3 table loads (L2/L3-hot; in flight across the barrier)
        bf16x8 bA[2], wf[2];
        bA[0] = *(const bf16x8*)(ab + (size_t)k3 * 1024);
        bA[1] = *(const bf16x8*)(ab + (size_t)k3 * 1024 + 512);
        wf[0] = *(const bf16x8*)(wb + (size_t)k3 * 16384);
        wf[1] = *(const bf16x8*)(wb + (size_t)k3 * 16384 + 32);

        if (k3 > 0) __syncthreads();   // previous conv reads done before overwrite

        // aggregation: D[(t=wave, c-block m), v] -> xagg (swizzled bf16)
#pragma unroll
        for (int m = 0; m < 4; ++m) {
#pragma unroll
            for (int n = 0; n < 2; ++n) {
                f32x4 d = __builtin_amdgcn_mfma_f32_16x16x32_bf16(xfrag[m], bA[n],
                                                                  zero4, 0, 0, 0);
                const int v = n * 16 + l15;
                if (v < 25) {
                    const int cc  = wave * 25 + v;
                    const int col = (m * 16 + lg * 4) ^ ((cc & 7) << 3);
                    bf16x4 h;
                    h[0] = (__bf16)d[0]; h[1] = (__bf16)d[1];
                    h[2] = (__bf16)d[2]; h[3] = (__bf16)d[3];
                    *(bf16x4*)((char*)xagg + cc * 128 + col * 2) = h;
                }
            }
        }
        __syncthreads();

        // conv: acc[cc-tile, o] += xagg[cc, c] * W[o, c]
#pragma unroll
        for (int mcc = 0; mcc < 7; ++mcc) {
            const int cc = mcc * 16 + l15;
            const int sw2 = (cc & 7) << 3;
#pragma unroll
            for (int ks = 0; ks < 2; ++ks) {
                const int col = (ks * 32 + lg * 8) ^ sw2;
                bf16x8 aF = *(const bf16x8*)((char*)xagg + cc * 128 + col * 2);
                acc[mcc] = __builtin_amdgcn_mfma_f32_16x16x32_bf16(aF, wf[ks],
                                                                   acc[mcc], 0, 0, 0);
            }
        }
        if (k3 < 2) __syncthreads();
    }

    // ---- epilogue: out = x + acc*inv + bias (residual from staged bf16 xs) ----
    const size_t obase = (size_t)(b * 256 + ch) * 3200 + tt * 100;
#pragma unroll
    for (int mcc = 0; mcc < 7; ++mcc) {
        const int cc0 = mcc * 16 + lg * 4;
        if (cc0 < 100) {
            f32x4 o4;
#pragma unroll
            for (int j = 0; j < 4; ++j) {
                const int cc = cc0 + j;
                const int t = cc / 25, v = cc - t * 25;
                const int gr = (((o_lane * 4 + t) << 2) | (v >> 3)) ^ (o_lane & 7);
                const float xr = (float)*(const __bf16*)((char*)xs + (gr << 4) + ((v & 7) << 1));
                o4[j] = xr + acc[mcc][j] * inv + bias;
            }
            *(f32x4*)(out + obase + cc0) = o4;
        }
    }
}

extern "C" void kernel_launch(void* const* d_in, const int* in_sizes, int n_in,
                              void* d_out, int out_size, void* d_ws, size_t ws_size,
                              hipStream_t stream) {
    const float* x     = (const float*)d_in[0];
    const float* A     = (const float*)d_in[1];
    const float* Wq    = (const float*)d_in[2];
    const float* Wk    = (const float*)d_in[3];
    const float* Wconv = (const float*)d_in[4];
    const float* alpha = (const float*)d_in[5];
    const float* gamma = (const float*)d_in[6];
    const float* beta  = (const float*)d_in[7];
    const float* rmean = (const float*)d_in[8];
    const float* rvar  = (const float*)d_in[9];
    float* out = (float*)d_out;

    float*  xm    = (float*)d_ws;
    __bf16* afull = (__bf16*)((char*)d_ws + 1638400);
    __bf16* wcb   = (__bf16*)((char*)d_ws + 2031616);

    k_tmean4<<<64 * 128, 256, 0, stream>>>(x, xm);
    k_adyn<<<64, 256, 0, stream>>>(xm, A, Wq, Wk, alpha, afull, Wconv, wcb);
    k_main7<<<64 * 4 * 32, 256, 0, stream>>>(x, wcb, afull, gamma, beta,
                                             rmean, rvar, out);
}